// Round 5
// baseline (211.431 us; speedup 1.0000x reference)
//
#include <hip/hip_runtime.h>

#define TOPK 10
#define CLIP 0.05f
#define EPSV 1e-8f
#define ALPHA1 2.0f
#define ALPHA_OTHER 0.5f
#define TCAND 2.5f     // candidate threshold; guarded by exact fallback
#define MAXC 256       // per-row candidate slots (lambda~60); fallback covers overflow
#define LN2F 0.69314718056f

// sortable packed key: (monotone float key << 32) | (C - col)
// larger packed = larger value; on equal value, smaller col wins (matches lax.top_k)
// NOTE: built from raw x bits -> top-k ordering is immune to sigmoid numerics.
__device__ __forceinline__ unsigned long long pack_vc(float v, int c, int C) {
  unsigned u = __float_as_uint(v);
  unsigned key = (u & 0x80000000u) ? ~u : (u | 0x80000000u);
  return ((unsigned long long)key << 32) | (unsigned)(C - c);
}
__device__ __forceinline__ float unpack_v(unsigned long long p) {
  unsigned key = (unsigned)(p >> 32);
  unsigned u = (key & 0x80000000u) ? (key & 0x7fffffffu) : ~key;
  return __uint_as_float(u);
}
__device__ __forceinline__ int unpack_c(unsigned long long p, int C) {
  return C - (int)(unsigned)(p & 0xffffffffu);
}

// (base * w) in LOG2 UNITS for one element; caller scales the final sum by ln2.
// pos = (y == 1). v_rcp instead of IEEE div (~1 ulp), native v_log2. (verified R4)
__device__ __forceinline__ float base_w(float xv, bool pos) {
  float u = __expf(-xv);                       // v_mul + v_exp
  float r = __builtin_amdgcn_rcpf(1.f + u);    // sigmoid, fast rcp (~1 ulp)
  float xneg = fminf(1.05f - r, 1.f);          // min(1 - p + clip, 1)
  float q = pos ? r : xneg;
  float b2 = __log2f(fmaxf(q, EPSV));          // log2(q)
  float t = 1.f - q;                           // 1 - pt
  float t2 = t * t;
  float w = pos ? t : t2 * t2;                 // gamma: pos=1, neg=4
  return b2 * w;                               // log2-units
}

// ---------------------------------------------------------------------------
// One block per row. Streaming phase uses global_load_lds (direct HBM->LDS,
// zero VGPRs held per in-flight byte) with a per-wave double buffer and
// counted vmcnt waits. Each wave stages/consumes ONLY its own 1KB slice of
// each buffer -> no __syncthreads in the streaming loop.
//
// vmcnt discipline: the counted wait `vmcnt(2)` is issued IMMEDIATELY after
// the 2 prefetch loads, so it only assumes "the 2 newest VMEM ops are the
// prefetch pair" -- all older ops (current tile's loads, stray gather loads)
// are forced complete. Partial tiles clamp per-lane addresses instead of
// masking lanes, keeping the instruction count wave-uniform.
// ---------------------------------------------------------------------------

__global__ __launch_bounds__(256) void asl_kernel(
    const float* __restrict__ x, const float* __restrict__ y,
    const int* __restrict__ compost, const int* __restrict__ recycle,
    const int* __restrict__ donate, const int* __restrict__ wl_map,
    float* __restrict__ out, int C, int n1, int n2, int n3)
{
  const int row = blockIdx.x;
  const float* xr = x + (size_t)row * (size_t)C;
  const float* yr = y + (size_t)row * (size_t)C;
  const int tid = threadIdx.x;
  const int lane = tid & 63;
  const int wave = tid >> 6;

  __shared__ float s_x[2][1024];               // 2 bufs x 256 float4
  __shared__ float s_y[2][1024];
  __shared__ int s_has[3];
  __shared__ unsigned s_cnt;
  __shared__ unsigned long long s_cand[MAXC];
  __shared__ float s_sum[4];
  __shared__ unsigned long long s_top[TOPK];

  if (tid < 3) s_has[tid] = 0;
  if (tid == 0) s_cnt = 0;
  __syncthreads();

  // early-issue whitelist gather: loads now, flags tested after the stream loop
  const int ntot = n1 + n2 + n3;
  float gflag = 0.f; int gwhich = -1;
  if (tid < ntot) {
    int colI;
    if (tid < n1)           { gwhich = 0; colI = compost[tid]; }
    else if (tid < n1 + n2) { gwhich = 1; colI = recycle[tid - n1]; }
    else                    { gwhich = 2; colI = donate[tid - n1 - n2]; }
    gflag = yr[colI];
  }

  float ssc = 0.f;  // scalar-edge contributions (log2 units)

#define PUSH(V, CCOL)                                                     \
  do {                                                                    \
    unsigned _i = atomicAdd(&s_cnt, 1u);                                  \
    if (_i < MAXC) s_cand[_i] = pack_vc((V), (CCOL), C);                  \
  } while (0)
#define PROC_DIRECT(XV, YV, COL)                                          \
  do {                                                                    \
    float _xv = (XV);                                                     \
    ssc += base_w(_xv, (YV) > 0.5f);                                      \
    if (_xv > TCAND) PUSH(_xv, (COL));                                    \
  } while (0)

  // alignment prologue: make float4 base 16B-aligned (row*C mod 4 varies)
  int lead = (int)((4u - ((unsigned)((size_t)row * (size_t)C) & 3u)) & 3u);
  if (lead > C) lead = C;
  for (int col = tid; col < lead; col += 256) PROC_DIRECT(xr[col], yr[col], col);

  const int nvec  = (C - lead) >> 2;           // # float4 in vector region
  const int nvec4 = nvec << 2;                 // # floats in vector region
  const float4* __restrict__ x4 = (const float4*)(xr + lead);
  const float4* __restrict__ y4 = (const float4*)(yr + lead);
  const int ntiles = (nvec + 255) >> 8;        // 256 float4 per block-tile

  const unsigned wl4 = (unsigned)(wave * 64 + lane);  // float4 slot in tile
  const int wbase = wave * 256;                        // float base of wave slice

  // stage tile T's wave-slice into LDS buffer B (2 VMEM ops, wave-uniform)
#define STAGE(T, B)                                                          \
  do {                                                                       \
    unsigned _g4 = (unsigned)(T) * 256u + wl4;                               \
    if (_g4 >= (unsigned)nvec) _g4 = (unsigned)nvec - 1u;  /* clamp dup */   \
    __builtin_amdgcn_global_load_lds(                                        \
        (__attribute__((address_space(1))) void*)(void*)(x4 + _g4),          \
        (__attribute__((address_space(3))) void*)(&s_x[(B)][wbase]),         \
        16, 0, 0);                                                           \
    __builtin_amdgcn_global_load_lds(                                        \
        (__attribute__((address_space(1))) void*)(void*)(y4 + _g4),          \
        (__attribute__((address_space(3))) void*)(&s_y[(B)][wbase]),         \
        16, 0, 0);                                                           \
  } while (0)

  float acc[4] = {0.f, 0.f, 0.f, 0.f};

  if (ntiles > 0) {
    STAGE(0, 0);
    int buf = 0;
    for (int t = 0; t < ntiles; ++t) {
      if (t + 1 < ntiles) {
        STAGE(t + 1, buf ^ 1);
        // wait for current tile (everything except the 2 prefetch ops)
        asm volatile("s_waitcnt vmcnt(2)" ::: "memory");
      } else {
        asm volatile("s_waitcnt vmcnt(0)" ::: "memory");
      }
      // consume this wave's slice: stride-64 floats -> bank = lane%32, 2-way (free)
      const int tb = t * 1024 + wbase;
#pragma unroll
      for (int k = 0; k < 4; ++k) {
        const int off  = k * 64 + lane;
        const int fidx = tb + off;               // float idx in vec region
        if (fidx < nvec4) {
          float xv = s_x[buf][wbase + off];
          float yv = s_y[buf][wbase + off];
          acc[k] += base_w(xv, yv > 0.5f);
          if (xv > TCAND) PUSH(xv, lead + fidx); // rare; execz-skipped
        }
      }
      buf ^= 1;
    }
  }

  // scalar tail (0-3 elements)
  for (int col = lead + nvec4 + tid; col < C; col += 256)
    PROC_DIRECT(xr[col], yr[col], col);

  // flush whitelist flags (benign write-1 races)
  if (gwhich >= 0 && gflag > 0.5f) s_has[gwhich] = 1;
  for (int i = 256 + tid; i < ntot; i += 256) {  // generic remainder (empty here)
    int which, colI;
    if (i < n1)           { which = 0; colI = compost[i]; }
    else if (i < n1 + n2) { which = 1; colI = recycle[i - n1]; }
    else                  { which = 2; colI = donate[i - n1 - n2]; }
    if (yr[colI] > 0.5f) s_has[which] = 1;
  }
#undef PROC_DIRECT
#undef PUSH
#undef STAGE

  // wave reduce the sum (log2 units)
  float sum = ssc + acc[0] + acc[1] + acc[2] + acc[3];
#pragma unroll
  for (int off = 32; off > 0; off >>= 1) sum += __shfl_xor(sum, off, 64);
  if (lane == 0) s_sum[wave] = sum;
  __syncthreads();

  // wave 0: exact top-10 selection
  if (wave == 0) {
    const unsigned cnt = s_cnt;
    unsigned long long ls[TOPK];   // per-lane sorted (desc) packed list; 0 = pad
#pragma unroll
    for (int s = 0; s < TOPK; s++) ls[s] = 0ULL;

#define INSERT(P)                                                          \
    do {                                                                   \
      unsigned long long _p = (P);                                         \
      if (_p > ls[TOPK - 1]) {                                             \
        _Pragma("unroll")                                                  \
        for (int _s = 0; _s < TOPK; _s++) {                                \
          bool _g = _p > ls[_s];                                           \
          unsigned long long _t = _g ? ls[_s] : _p;                        \
          ls[_s] = _g ? _p : ls[_s];                                       \
          _p = _t;                                                         \
        }                                                                  \
      }                                                                    \
    } while (0)

    if (cnt >= TOPK && cnt <= MAXC) {
      for (unsigned i = lane; i < cnt; i += 64) INSERT(s_cand[i]);
    } else {
      // exact fallback: rescan the (cache-resident) row
      for (int col = lane; col < C; col += 64) INSERT(pack_vc(xr[col], col, C));
    }
#undef INSERT

    // 10 rounds of 64-lane packed max; pop winner (packed values unique)
    for (int r = 0; r < TOPK; r++) {
      unsigned long long mine = ls[0];
      unsigned long long best = mine;
#pragma unroll
      for (int off = 32; off > 0; off >>= 1) {
        unsigned long long o = __shfl_xor(best, off, 64);
        best = (o > best) ? o : best;
      }
      if (lane == 0) s_top[r] = best;
      if (mine == best) {
#pragma unroll
        for (int s = 0; s < TOPK - 1; s++) ls[s] = ls[s + 1];
        ls[TOPK - 1] = 0ULL;
      }
    }
  }
  __syncthreads();

  if (tid == 0) {
    float total = s_sum[0] + s_sum[1] + s_sum[2] + s_sum[3];
    const bool h1 = s_has[0] != 0, h2 = s_has[1] != 0, h3 = s_has[2] != 0;
    const bool gt4 = !(h1 || h2 || h3);

    // rank-sequential multiplier logic (mirrors the lax.scan)
    bool found = false;
    float fr[TOPK];
#pragma unroll
    for (int r = 0; r < TOPK; r++) {
      int col = unpack_c(s_top[r], C);
      int wl = wl_map[col];
      bool in_map = wl > 0;
      bool in_gt = (wl == 1 && h1) || (wl == 2 && h2) ||
                   (wl == 3 && h3) || (wl == 4 && gt4);
      float f = 1.f;
      if (in_map && gt4) f *= ALPHA_OTHER;
      if (in_map && !in_gt && !found) f *= ALPHA1;
      fr[r] = f;
      found = found || (in_map && in_gt);
    }
    const float extra = found ? 1.f : ALPHA1;
#pragma unroll
    for (int r = 0; r < TOPK; r++) {
      float mult = fr[r] * extra;
      if (mult != 1.f) {
        int col = unpack_c(s_top[r], C);
        float xv = unpack_v(s_top[r]);
        float bwv = base_w(xv, yr[col] > 0.5f);   // log2 units, consistent
        total += (mult - 1.f) * bwv;
      }
    }
    atomicAdd(out, -total * LN2F);   // scale log2-units -> natural log once
  }
}

extern "C" void kernel_launch(void* const* d_in, const int* in_sizes, int n_in,
                              void* d_out, int out_size, void* d_ws, size_t ws_size,
                              hipStream_t stream) {
  const float* x       = (const float*)d_in[0];
  const float* y       = (const float*)d_in[1];
  const int*   compost = (const int*)d_in[2];
  const int*   recycle = (const int*)d_in[3];
  const int*   donate  = (const int*)d_in[4];
  const int*   wl_map  = (const int*)d_in[5];
  float* out = (float*)d_out;

  const int C  = in_sizes[5];
  const int B  = in_sizes[0] / C;
  const int n1 = in_sizes[2], n2 = in_sizes[3], n3 = in_sizes[4];

  hipMemsetAsync(out, 0, sizeof(float), stream);
  asl_kernel<<<B, 256, 0, stream>>>(x, y, compost, recycle, donate, wl_map,
                                    out, C, n1, n2, n3);
}

// Round 6
// 207.845 us; speedup vs baseline: 1.0173x; 1.0173x over previous
//
#include <hip/hip_runtime.h>

#define TOPK 10
#define CLIP 0.05f
#define EPSV 1e-8f
#define ALPHA1 2.0f
#define ALPHA_OTHER 0.5f
#define TCAND 2.5f     // candidate threshold; guarded by exact fallback
#define MAXC 256       // per-row candidate slots (lambda~60); fallback covers overflow
#define LN2F 0.69314718056f

// sortable packed key: (monotone float key << 32) | (C - col)
// larger packed = larger value; on equal value, smaller col wins (matches lax.top_k)
// NOTE: built from raw x bits -> top-k ordering is immune to sigmoid numerics.
__device__ __forceinline__ unsigned long long pack_vc(float v, int c, int C) {
  unsigned u = __float_as_uint(v);
  unsigned key = (u & 0x80000000u) ? ~u : (u | 0x80000000u);
  return ((unsigned long long)key << 32) | (unsigned)(C - c);
}
__device__ __forceinline__ float unpack_v(unsigned long long p) {
  unsigned key = (unsigned)(p >> 32);
  unsigned u = (key & 0x80000000u) ? (key & 0x7fffffffu) : ~key;
  return __uint_as_float(u);
}
__device__ __forceinline__ int unpack_c(unsigned long long p, int C) {
  return C - (int)(unsigned)(p & 0xffffffffu);
}

// (base * w) in LOG2 UNITS for one element; caller scales the final sum by ln2.
// pos = (y == 1). v_rcp instead of IEEE div (~1 ulp), native v_log2. (verified R4/R5)
__device__ __forceinline__ float base_w(float xv, bool pos) {
  float u = __expf(-xv);                       // v_mul + v_exp
  float r = __builtin_amdgcn_rcpf(1.f + u);    // sigmoid, fast rcp (~1 ulp)
  float xneg = fminf(1.05f - r, 1.f);          // min(1 - p + clip, 1)
  float q = pos ? r : xneg;
  float b2 = __log2f(fmaxf(q, EPSV));          // log2(q)
  float t = 1.f - q;                           // 1 - pt
  float t2 = t * t;
  float w = pos ? t : t2 * t2;                 // gamma: pos=1, neg=4
  return b2 * w;                               // log2-units
}

// ---------------------------------------------------------------------------
// One block per row. Streaming phase: DEPTH-4 quad-buffered global_load_lds
// pipeline (8 VMEM ops / 8 KB in flight per wave -- the compiler cannot sink
// these to save registers). Counted per-wave vmcnt waits; no __syncthreads in
// the streaming loop (each wave owns its own LDS slices).
//
// vmcnt discipline: vmcnt counts retire IN ISSUE ORDER (m135), so a wait of
// vmcnt(6) after 8 outstanding stage-ops forces the OLDEST pair (the tile we
// are about to consume) complete -- also flushing any earlier stray loads
// (whitelist gather). Partial tiles clamp per-lane global addresses instead
// of masking lanes, keeping instruction count wave-uniform.
// lgkmcnt(0) before re-staging a buffer guards ds_read vs DMA-overwrite.
// ---------------------------------------------------------------------------

__global__ __launch_bounds__(256) void asl_kernel(
    const float* __restrict__ x, const float* __restrict__ y,
    const int* __restrict__ compost, const int* __restrict__ recycle,
    const int* __restrict__ donate, const int* __restrict__ wl_map,
    float* __restrict__ out, int C, int n1, int n2, int n3)
{
  const int row = blockIdx.x;
  const float* xr = x + (size_t)row * (size_t)C;
  const float* yr = y + (size_t)row * (size_t)C;
  const int tid = threadIdx.x;
  const int lane = tid & 63;
  const int wave = tid >> 6;

  __shared__ float s_x[4][1024];               // 4 bufs x 256 float4
  __shared__ float s_y[4][1024];
  __shared__ int s_has[3];
  __shared__ unsigned s_cnt;
  __shared__ unsigned long long s_cand[MAXC];
  __shared__ float s_sum[4];
  __shared__ unsigned long long s_top[TOPK];

  if (tid < 3) s_has[tid] = 0;
  if (tid == 0) s_cnt = 0;
  __syncthreads();

  // early-issue whitelist gather: loads now, flags tested after the stream loop
  const int ntot = n1 + n2 + n3;
  float gflag = 0.f; int gwhich = -1;
  if (tid < ntot) {
    int colI;
    if (tid < n1)           { gwhich = 0; colI = compost[tid]; }
    else if (tid < n1 + n2) { gwhich = 1; colI = recycle[tid - n1]; }
    else                    { gwhich = 2; colI = donate[tid - n1 - n2]; }
    gflag = yr[colI];
  }

  float ssc = 0.f;  // scalar-edge contributions (log2 units)

#define PUSH(V, CCOL)                                                     \
  do {                                                                    \
    unsigned _i = atomicAdd(&s_cnt, 1u);                                  \
    if (_i < MAXC) s_cand[_i] = pack_vc((V), (CCOL), C);                  \
  } while (0)
#define PROC_DIRECT(XV, YV, COL)                                          \
  do {                                                                    \
    float _xv = (XV);                                                     \
    ssc += base_w(_xv, (YV) > 0.5f);                                      \
    if (_xv > TCAND) PUSH(_xv, (COL));                                    \
  } while (0)

  // alignment prologue: make float4 base 16B-aligned (row*C mod 4 varies)
  int lead = (int)((4u - ((unsigned)((size_t)row * (size_t)C) & 3u)) & 3u);
  if (lead > C) lead = C;
  for (int col = tid; col < lead; col += 256) PROC_DIRECT(xr[col], yr[col], col);

  const int nvec  = (C - lead) >> 2;           // # float4 in vector region
  const int nvec4 = nvec << 2;                 // # floats in vector region
  const float4* __restrict__ x4 = (const float4*)(xr + lead);
  const float4* __restrict__ y4 = (const float4*)(yr + lead);
  const int ntiles = (nvec + 255) >> 8;        // 256 float4 per block-tile

  const unsigned wl4 = (unsigned)(wave * 64 + lane);  // float4 slot in tile
  const int wbase = wave * 256;                        // float base of wave slice

  // stage tile T's wave-slice into LDS buffer B (2 VMEM ops, wave-uniform)
#define STAGE(T, B)                                                          \
  do {                                                                       \
    unsigned _g4 = (unsigned)(T) * 256u + wl4;                               \
    if (_g4 >= (unsigned)nvec) _g4 = (unsigned)nvec - 1u;  /* clamp dup */   \
    __builtin_amdgcn_global_load_lds(                                        \
        (__attribute__((address_space(1))) void*)(void*)(x4 + _g4),          \
        (__attribute__((address_space(3))) void*)(&s_x[(B)][wbase]),         \
        16, 0, 0);                                                           \
    __builtin_amdgcn_global_load_lds(                                        \
        (__attribute__((address_space(1))) void*)(void*)(y4 + _g4),          \
        (__attribute__((address_space(3))) void*)(&s_y[(B)][wbase]),         \
        16, 0, 0);                                                           \
  } while (0)

  float4 accv = make_float4(0.f, 0.f, 0.f, 0.f);

  if (ntiles > 0) {
    int issued = 0;
    for (; issued < 4 && issued < ntiles; ++issued) STAGE(issued, issued);

    for (int t = 0; t < ntiles; ++t) {
      const int rem = issued - t - 1;    // prefetch pairs in flight after tile t retires
      if (rem >= 3)      asm volatile("s_waitcnt vmcnt(6)" ::: "memory");
      else if (rem == 2) asm volatile("s_waitcnt vmcnt(4)" ::: "memory");
      else if (rem == 1) asm volatile("s_waitcnt vmcnt(2)" ::: "memory");
      else               asm volatile("s_waitcnt vmcnt(0)" ::: "memory");

      const int buf = t & 3;
      const unsigned g4t = (unsigned)t * 256u + wl4;
      // lane-contiguous float4 (matches the DMA's lane-major layout): ds_read_b128
      const float4 X = *(const float4*)&s_x[buf][wbase + lane * 4];
      const float4 Y = *(const float4*)&s_y[buf][wbase + lane * 4];

      if (g4t < (unsigned)nvec) {        // whole float4 valid (clamped dups skipped)
        const int cb = lead + (int)(g4t * 4u);
        accv.x += base_w(X.x, Y.x > 0.5f);
        accv.y += base_w(X.y, Y.y > 0.5f);
        accv.z += base_w(X.z, Y.z > 0.5f);
        accv.w += base_w(X.w, Y.w > 0.5f);
        const float mx = fmaxf(fmaxf(X.x, X.y), fmaxf(X.z, X.w));
        if (mx > TCAND) {                // rare; execz-skipped
          if (X.x > TCAND) PUSH(X.x, cb + 0);
          if (X.y > TCAND) PUSH(X.y, cb + 1);
          if (X.z > TCAND) PUSH(X.z, cb + 2);
          if (X.w > TCAND) PUSH(X.w, cb + 3);
        }
      }

      // guard: ds_reads of buf must retire before the DMA re-targets it
      asm volatile("s_waitcnt lgkmcnt(0)" ::: "memory");
      if (issued < ntiles) { STAGE(issued, issued & 3); ++issued; }
    }
  }

  // scalar tail (0-3 elements)
  for (int col = lead + nvec4 + tid; col < C; col += 256)
    PROC_DIRECT(xr[col], yr[col], col);

  // flush whitelist flags (benign write-1 races)
  if (gwhich >= 0 && gflag > 0.5f) s_has[gwhich] = 1;
  for (int i = 256 + tid; i < ntot; i += 256) {  // generic remainder (empty here)
    int which, colI;
    if (i < n1)           { which = 0; colI = compost[i]; }
    else if (i < n1 + n2) { which = 1; colI = recycle[i - n1]; }
    else                  { which = 2; colI = donate[i - n1 - n2]; }
    if (yr[colI] > 0.5f) s_has[which] = 1;
  }
#undef PROC_DIRECT
#undef PUSH
#undef STAGE

  // wave reduce the sum (log2 units)
  float sum = ssc + accv.x + accv.y + accv.z + accv.w;
#pragma unroll
  for (int off = 32; off > 0; off >>= 1) sum += __shfl_xor(sum, off, 64);
  if (lane == 0) s_sum[wave] = sum;
  __syncthreads();

  // wave 0: exact top-10 selection
  if (wave == 0) {
    const unsigned cnt = s_cnt;
    unsigned long long ls[TOPK];   // per-lane sorted (desc) packed list; 0 = pad
#pragma unroll
    for (int s = 0; s < TOPK; s++) ls[s] = 0ULL;

#define INSERT(P)                                                          \
    do {                                                                   \
      unsigned long long _p = (P);                                         \
      if (_p > ls[TOPK - 1]) {                                             \
        _Pragma("unroll")                                                  \
        for (int _s = 0; _s < TOPK; _s++) {                                \
          bool _g = _p > ls[_s];                                           \
          unsigned long long _t = _g ? ls[_s] : _p;                        \
          ls[_s] = _g ? _p : ls[_s];                                       \
          _p = _t;                                                         \
        }                                                                  \
      }                                                                    \
    } while (0)

    if (cnt >= TOPK && cnt <= MAXC) {
      for (unsigned i = lane; i < cnt; i += 64) INSERT(s_cand[i]);
    } else {
      // exact fallback: rescan the (cache-resident) row
      for (int col = lane; col < C; col += 64) INSERT(pack_vc(xr[col], col, C));
    }
#undef INSERT

    // 10 rounds of 64-lane packed max; pop winner (packed values unique)
    for (int r = 0; r < TOPK; r++) {
      unsigned long long mine = ls[0];
      unsigned long long best = mine;
#pragma unroll
      for (int off = 32; off > 0; off >>= 1) {
        unsigned long long o = __shfl_xor(best, off, 64);
        best = (o > best) ? o : best;
      }
      if (lane == 0) s_top[r] = best;
      if (mine == best) {
#pragma unroll
        for (int s = 0; s < TOPK - 1; s++) ls[s] = ls[s + 1];
        ls[TOPK - 1] = 0ULL;
      }
    }
  }
  __syncthreads();

  if (tid == 0) {
    float total = s_sum[0] + s_sum[1] + s_sum[2] + s_sum[3];
    const bool h1 = s_has[0] != 0, h2 = s_has[1] != 0, h3 = s_has[2] != 0;
    const bool gt4 = !(h1 || h2 || h3);

    // rank-sequential multiplier logic (mirrors the lax.scan)
    bool found = false;
    float fr[TOPK];
#pragma unroll
    for (int r = 0; r < TOPK; r++) {
      int col = unpack_c(s_top[r], C);
      int wl = wl_map[col];
      bool in_map = wl > 0;
      bool in_gt = (wl == 1 && h1) || (wl == 2 && h2) ||
                   (wl == 3 && h3) || (wl == 4 && gt4);
      float f = 1.f;
      if (in_map && gt4) f *= ALPHA_OTHER;
      if (in_map && !in_gt && !found) f *= ALPHA1;
      fr[r] = f;
      found = found || (in_map && in_gt);
    }
    const float extra = found ? 1.f : ALPHA1;
#pragma unroll
    for (int r = 0; r < TOPK; r++) {
      float mult = fr[r] * extra;
      if (mult != 1.f) {
        int col = unpack_c(s_top[r], C);
        float xv = unpack_v(s_top[r]);
        float bwv = base_w(xv, yr[col] > 0.5f);   // log2 units, consistent
        total += (mult - 1.f) * bwv;
      }
    }
    atomicAdd(out, -total * LN2F);   // scale log2-units -> natural log once
  }
}

extern "C" void kernel_launch(void* const* d_in, const int* in_sizes, int n_in,
                              void* d_out, int out_size, void* d_ws, size_t ws_size,
                              hipStream_t stream) {
  const float* x       = (const float*)d_in[0];
  const float* y       = (const float*)d_in[1];
  const int*   compost = (const int*)d_in[2];
  const int*   recycle = (const int*)d_in[3];
  const int*   donate  = (const int*)d_in[4];
  const int*   wl_map  = (const int*)d_in[5];
  float* out = (float*)d_out;

  const int C  = in_sizes[5];
  const int B  = in_sizes[0] / C;
  const int n1 = in_sizes[2], n2 = in_sizes[3], n3 = in_sizes[4];

  hipMemsetAsync(out, 0, sizeof(float), stream);
  asl_kernel<<<B, 256, 0, stream>>>(x, y, compost, recycle, donate, wl_map,
                                    out, C, n1, n2, n3);
}